// Round 3
// baseline (139.029 us; speedup 1.0000x reference)
//
#include <hip/hip_runtime.h>

// BlockinnerAttention: b=1, h=8, T_q=2048, T=4096, dk=64, BS=64, top-2 blocks/query.
// Round 3: bucket queries by (head, block); one WG per bucket keeps the K/V
// block in REGISTERS (kreg/vreg, round-2 fragment layout) and amortizes it over
// ~64 queries. Each (q,slot) entry -> partial (m, l, unnormalized o) in ws;
// combine kernel merges the 2 partials per query (exact flash-style combine).
// Pipeline: memset(hist) -> hist -> scan(1 WG) -> scatter -> bucket -> combine.

#define NH      8
#define TQ      2048
#define TKV     4096
#define DK      64
#define BSZ     64
#define NB      (TKV / BSZ)     // 64 blocks per head
#define NQ_TOT  (NH * TQ)       // 16384
#define NENT    (NQ_TOT * 2)    // 32768
#define NBUCKET (NH * NB)       // 512

// ws layout (bytes):
//   [0,      2048)   hist    (512 int)
//   [2048,   4100)   offsets (513 int)
//   [4160,   6208)   cursor  (512 int)
//   [8192, 139264)   list    (32768 int)
//   [139264, +8.9MB) partials: 32768 entries x 68 floats (o[64], m, l, pad)
#define WS_OFFSETS_B 2048
#define WS_CURSOR_B  4160
#define WS_LIST_B    8192
#define WS_PART_B    139264
#define WS_NEEDED    (WS_PART_B + (size_t)NENT * 68 * 4)

__global__ __launch_bounds__(256) void hist_kernel(
    const int* __restrict__ top2, int* __restrict__ hist)
{
    const int e = blockIdx.x * 256 + threadIdx.x;   // 0..NENT-1
    const int qi = e >> 1;
    const int blk = top2[e];
    atomicAdd(hist + (((qi >> 11) << 6) | blk), 1);
}

__global__ __launch_bounds__(NBUCKET) void scan_kernel(
    const int* __restrict__ hist, int* __restrict__ offsets, int* __restrict__ cursor)
{
    __shared__ int sh[NBUCKET];
    const int t = threadIdx.x;
    sh[t] = hist[t];
    __syncthreads();
    for (int d = 1; d < NBUCKET; d <<= 1) {
        int vv = sh[t];
        int add = (t >= d) ? sh[t - d] : 0;
        __syncthreads();
        sh[t] = vv + add;
        __syncthreads();
    }
    const int excl = (t == 0) ? 0 : sh[t - 1];
    offsets[t] = excl;
    cursor[t] = excl;
    if (t == NBUCKET - 1) offsets[NBUCKET] = sh[t];
}

__global__ __launch_bounds__(256) void scatter_kernel(
    const int* __restrict__ top2, int* __restrict__ cursor, int* __restrict__ list)
{
    const int e = blockIdx.x * 256 + threadIdx.x;
    const int qi = e >> 1;
    const int blk = top2[e];
    const int pos = atomicAdd(cursor + (((qi >> 11) << 6) | blk), 1);
    list[pos] = e;
}

__global__ __launch_bounds__(256, 2) void bucket_kernel(
    const float* __restrict__ q,
    const float* __restrict__ k,
    const float* __restrict__ v,
    const int*   __restrict__ offsets,
    const int*   __restrict__ list,
    float*       __restrict__ partials)
{
    const int bucket = blockIdx.x;
    const int h    = bucket >> 6;
    const int blk  = bucket & (NB - 1);
    const int wave = threadIdx.x >> 6;
    const int lane = threadIdx.x & 63;
    const int g    = lane >> 4;     // row-in-chunk 0..3
    const int dc   = lane & 15;     // dim chunk 0..15

    const int start = offsets[bucket];
    const int nq    = offsets[bucket + 1] - start;
    if (nq == 0) return;

    // K/V block resident in registers: kreg[i] = K[4i+g][4dc..4dc+3]
    const size_t base = ((size_t)h * TKV + (size_t)blk * BSZ) * DK + g * DK + dc * 4;
    float4 kreg[16], vreg[16];
#pragma unroll
    for (int i = 0; i < 16; ++i) kreg[i] = *(const float4*)(k + base + i * 256);
#pragma unroll
    for (int i = 0; i < 16; ++i) vreg[i] = *(const float4*)(v + base + i * 256);

    for (int it = wave; it < nq; it += 4) {
        const int e  = list[start + it];
        const int qi = e >> 1;
        const float4 qf = *(const float4*)(q + (size_t)qi * DK + dc * 4);

        // scores for rows 4i+g (group-reduced over dc)
        float sc[16];
#pragma unroll
        for (int i = 0; i < 16; ++i) {
            const float4 a = kreg[i];
            float p = a.x * qf.x + a.y * qf.y + a.z * qf.z + a.w * qf.w;
            p += __shfl_xor(p, 1);
            p += __shfl_xor(p, 2);
            p += __shfl_xor(p, 4);
            p += __shfl_xor(p, 8);
            sc[i] = p * 0.125f;     // 1/sqrt(64)
        }

        // block-local softmax partial (m, l) over all 64 rows
        float m = sc[0];
#pragma unroll
        for (int i = 1; i < 16; ++i) m = fmaxf(m, sc[i]);
        m = fmaxf(m, __shfl_xor(m, 16));
        m = fmaxf(m, __shfl_xor(m, 32));

        float l = 0.f;
#pragma unroll
        for (int i = 0; i < 16; ++i) { sc[i] = __expf(sc[i] - m); l += sc[i]; }
        l += __shfl_xor(l, 16);
        l += __shfl_xor(l, 32);

        // unnormalized o = sum_j w_j * V[j][:]
        float4 acc = make_float4(0.f, 0.f, 0.f, 0.f);
#pragma unroll
        for (int i = 0; i < 16; ++i) {
            const float w = sc[i];
            acc.x += vreg[i].x * w; acc.y += vreg[i].y * w;
            acc.z += vreg[i].z * w; acc.w += vreg[i].w * w;
        }
        acc.x += __shfl_xor(acc.x, 16); acc.y += __shfl_xor(acc.y, 16);
        acc.z += __shfl_xor(acc.z, 16); acc.w += __shfl_xor(acc.w, 16);
        acc.x += __shfl_xor(acc.x, 32); acc.y += __shfl_xor(acc.y, 32);
        acc.z += __shfl_xor(acc.z, 32); acc.w += __shfl_xor(acc.w, 32);

        float* p = partials + (size_t)e * 68;
        if (g == 0) *(float4*)(p + dc * 4) = acc;
        if (lane == 0) { p[64] = m; p[65] = l; }
    }
}

__global__ __launch_bounds__(256) void combine_kernel(
    const float* __restrict__ partials, float* __restrict__ out)
{
    const int t  = blockIdx.x * 256 + threadIdx.x;  // NQ_TOT*16 threads
    const int qi = t >> 4;
    const int dc = t & 15;
    const float* p0 = partials + (size_t)(qi * 2) * 68;
    const float* p1 = p0 + 68;
    const float m0 = p0[64], l0 = p0[65];
    const float m1 = p1[64], l1 = p1[65];
    const float m  = fmaxf(m0, m1);
    const float a0 = __expf(m0 - m), a1 = __expf(m1 - m);
    const float inv = 1.0f / (a0 * l0 + a1 * l1);
    const float4 o0 = *(const float4*)(p0 + dc * 4);
    const float4 o1 = *(const float4*)(p1 + dc * 4);
    float4 o;
    o.x = (o0.x * a0 + o1.x * a1) * inv;
    o.y = (o0.y * a0 + o1.y * a1) * inv;
    o.z = (o0.z * a0 + o1.z * a1) * inv;
    o.w = (o0.w * a0 + o1.w * a1) * inv;
    *(float4*)(out + (size_t)qi * DK + dc * 4) = o;
}

// ---------------- fallback (round-2 kernel, ws-free) ----------------
__global__ __launch_bounds__(256) void blockattn_fallback(
    const float* __restrict__ q, const float* __restrict__ k,
    const float* __restrict__ v, const int* __restrict__ top2,
    float* __restrict__ out)
{
    const int wave = threadIdx.x >> 6;
    const int lane = threadIdx.x & 63;
    const int qidx = (blockIdx.x << 2) + wave;
    const int bh   = qidx >> 11;
    const int g    = lane >> 4;
    const int dc   = lane & 15;

    const int2 idx = *(const int2*)(top2 + (size_t)qidx * 2);
    const size_t bh_off = (size_t)bh * (TKV * DK);
    const int off = g * DK + dc * 4;

    const float* kb0 = k + bh_off + (size_t)idx.x * (BSZ * DK) + off;
    const float* kb1 = k + bh_off + (size_t)idx.y * (BSZ * DK) + off;
    const float* vb0 = v + bh_off + (size_t)idx.x * (BSZ * DK) + off;
    const float* vb1 = v + bh_off + (size_t)idx.y * (BSZ * DK) + off;
    const float4 qf = *(const float4*)(q + (size_t)qidx * DK + dc * 4);

    float sc[32];
#pragma unroll
    for (int i = 0; i < 16; ++i) {
        const float4 a = *(const float4*)(kb0 + i * 256);
        float p = a.x*qf.x + a.y*qf.y + a.z*qf.z + a.w*qf.w;
        p += __shfl_xor(p,1); p += __shfl_xor(p,2); p += __shfl_xor(p,4); p += __shfl_xor(p,8);
        sc[i] = p * 0.125f;
    }
#pragma unroll
    for (int i = 0; i < 16; ++i) {
        const float4 a = *(const float4*)(kb1 + i * 256);
        float p = a.x*qf.x + a.y*qf.y + a.z*qf.z + a.w*qf.w;
        p += __shfl_xor(p,1); p += __shfl_xor(p,2); p += __shfl_xor(p,4); p += __shfl_xor(p,8);
        sc[16+i] = p * 0.125f;
    }
    float m = sc[0];
#pragma unroll
    for (int i = 1; i < 32; ++i) m = fmaxf(m, sc[i]);
    m = fmaxf(m, __shfl_xor(m,16)); m = fmaxf(m, __shfl_xor(m,32));
    float sum = 0.f;
#pragma unroll
    for (int i = 0; i < 32; ++i) { sc[i] = __expf(sc[i]-m); sum += sc[i]; }
    sum += __shfl_xor(sum,16); sum += __shfl_xor(sum,32);
    const float inv = 1.0f / sum;

    float4 acc = make_float4(0.f,0.f,0.f,0.f);
#pragma unroll
    for (int i = 0; i < 16; ++i) {
        const float4 a = *(const float4*)(vb0 + i * 256);
        acc.x += a.x*sc[i]; acc.y += a.y*sc[i]; acc.z += a.z*sc[i]; acc.w += a.w*sc[i];
    }
#pragma unroll
    for (int i = 0; i < 16; ++i) {
        const float4 a = *(const float4*)(vb1 + i * 256);
        acc.x += a.x*sc[16+i]; acc.y += a.y*sc[16+i]; acc.z += a.z*sc[16+i]; acc.w += a.w*sc[16+i];
    }
    acc.x += __shfl_xor(acc.x,16); acc.y += __shfl_xor(acc.y,16);
    acc.z += __shfl_xor(acc.z,16); acc.w += __shfl_xor(acc.w,16);
    acc.x += __shfl_xor(acc.x,32); acc.y += __shfl_xor(acc.y,32);
    acc.z += __shfl_xor(acc.z,32); acc.w += __shfl_xor(acc.w,32);

    if (g == 0) {
        float4 o;
        o.x = acc.x*inv; o.y = acc.y*inv; o.z = acc.z*inv; o.w = acc.w*inv;
        *(float4*)(out + (size_t)qidx * DK + dc * 4) = o;
    }
}

extern "C" void kernel_launch(void* const* d_in, const int* in_sizes, int n_in,
                              void* d_out, int out_size, void* d_ws, size_t ws_size,
                              hipStream_t stream) {
    const float* q    = (const float*)d_in[0];
    const float* k    = (const float*)d_in[1];
    const float* v    = (const float*)d_in[2];
    // d_in[3] is the scalar BS (=64), baked into kernel constants.
    const int*   top2 = (const int*)d_in[4];
    float*       out  = (float*)d_out;

    if (ws_size < WS_NEEDED) {
        dim3 grid(NQ_TOT / 4), block(256);
        hipLaunchKernelGGL(blockattn_fallback, grid, block, 0, stream, q, k, v, top2, out);
        return;
    }

    char* ws = (char*)d_ws;
    int* hist     = (int*)ws;
    int* offsets  = (int*)(ws + WS_OFFSETS_B);
    int* cursor   = (int*)(ws + WS_CURSOR_B);
    int* list     = (int*)(ws + WS_LIST_B);
    float* parts  = (float*)(ws + WS_PART_B);

    hipMemsetAsync(hist, 0, NBUCKET * sizeof(int), stream);
    hipLaunchKernelGGL(hist_kernel,    dim3(NENT / 256), dim3(256), 0, stream, top2, hist);
    hipLaunchKernelGGL(scan_kernel,    dim3(1),          dim3(NBUCKET), 0, stream, hist, offsets, cursor);
    hipLaunchKernelGGL(scatter_kernel, dim3(NENT / 256), dim3(256), 0, stream, top2, cursor, list);
    hipLaunchKernelGGL(bucket_kernel,  dim3(NBUCKET),    dim3(256), 0, stream, q, k, v, offsets, list, parts);
    hipLaunchKernelGGL(combine_kernel, dim3(NQ_TOT * 16 / 256), dim3(256), 0, stream, parts, out);
}